// Round 1
// baseline (66.396 us; speedup 1.0000x reference)
//
#include <hip/hip_runtime.h>
#include <math.h>

#define DIM 1280
#define BATCH_THREADS 320   // 320 threads * 4 cols = 1280 = DIM

// out[b][i] = i%2==0 ? sin(time[b]*rate(i)) : cos(time[b]*rate(i))
// rate(i) = 10000^(-(i//2)/640) = exp2(-(i//2) * log2(10000)/640)
__global__ __launch_bounds__(BATCH_THREADS)
void time_emb_kernel(const float* __restrict__ time, float* __restrict__ out, int batch) {
    const int t = threadIdx.x;           // 0..319, owns columns 4t..4t+3
    // pair indices k = i//2 for this thread's 4 columns: 2t (cols 4t,4t+1), 2t+1 (cols 4t+2,4t+3)
    const float L_over_640 = 13.287712379549449f / 640.0f;  // log2(10000)/640
    const float rate0 = exp2f(-(float)(2 * t)     * L_over_640);
    const float rate1 = exp2f(-(float)(2 * t + 1) * L_over_640);

    for (int b = blockIdx.x; b < batch; b += gridDim.x) {
        const float tv = time[b];        // wave-uniform broadcast load
        float s0, c0, s1, c1;
        __sincosf(tv * rate0, &s0, &c0);
        __sincosf(tv * rate1, &s1, &c1);
        // col 4t   (even) -> sin(a0); col 4t+1 (odd) -> cos(a0)
        // col 4t+2 (even) -> sin(a1); col 4t+3 (odd) -> cos(a1)
        float4 v = make_float4(s0, c0, s1, c1);
        *reinterpret_cast<float4*>(out + (size_t)b * DIM + (t << 2)) = v;
    }
}

extern "C" void kernel_launch(void* const* d_in, const int* in_sizes, int n_in,
                              void* d_out, int out_size, void* d_ws, size_t ws_size,
                              hipStream_t stream) {
    const float* time = (const float*)d_in[0];
    float* out = (float*)d_out;
    const int batch = in_sizes[0];       // 65536

    const int grid = 2048;               // grid-stride over rows; 8 blocks/CU
    time_emb_kernel<<<grid, BATCH_THREADS, 0, stream>>>(time, out, batch);
}